// Round 13
// baseline (62.002 us; speedup 1.0000x reference)
//
#include <hip/hip_runtime.h>
#include <hip/hip_bf16.h>

typedef short bfrag8 __attribute__((ext_vector_type(8)));
typedef float f32x4v __attribute__((ext_vector_type(4)));
typedef unsigned short U16;
typedef unsigned int U32;

#define NN 4096
#define DD 128

static __device__ __forceinline__ U16 f2bf(float f){
  union { __hip_bfloat16 b; U16 u; } cv;
  cv.b = __float2bfloat16(f);
  return cv.u;
}

static __device__ __forceinline__ float bf2f(U32 u){
  union { float f; U32 u; } cv;
  cv.u = u << 16;
  return cv.f;
}

// A-fragment from inverted adjacency bits (low byte): bit=0 -> 1.0bf16, bit=1 -> 0
static __device__ __forceinline__ bfrag8 afragb(U32 y){
  bfrag8 a;
  #pragma unroll
  for (int e = 0; e < 8; ++e) a[e] = (y & (1u<<e)) ? (short)0 : (short)0x3F80;
  return a;
}

// ---------------- kernel 0: adj pack TRANSPOSED (blocks 0..2047) + W^T (2048..2111) --
// adjbT[g*4096 + row] bit j = adj[row][g*32 + j] != 0  (g = 32-col group).
__global__ __launch_bounds__(256) void k0_combo(const int* __restrict__ adj,
                                                U32* __restrict__ adjbT,
                                                const float* __restrict__ W,
                                                U16* __restrict__ WT){
  if (blockIdx.x >= 2048){
    int i = (blockIdx.x - 2048)*256 + threadIdx.x;  // i = d*128 + dp
    int d = i >> 7, dp = i & 127;
    WT[dp*128 + d] = f2bf(W[i]);
    return;
  }
  const int g   = blockIdx.x >> 4;                  // 0..127
  const int row = (blockIdx.x & 15)*256 + threadIdx.x;
  const int4* src = reinterpret_cast<const int4*>(adj + (size_t)row*NN + g*32);
  int4 v[8];
  #pragma unroll
  for (int c = 0; c < 8; ++c) v[c] = src[c];
  U32 m = 0;
  #pragma unroll
  for (int c = 0; c < 8; ++c){
    m |= (v[c].x != 0 ? 1u : 0u) << (c*4);
    m |= (v[c].y != 0 ? 2u : 0u) << (c*4);
    m |= (v[c].z != 0 ? 4u : 0u) << (c*4);
    m |= (v[c].w != 0 ? 8u : 0u) << (c*4);
  }
  adjbT[(size_t)g*4096 + row] = m;
}

// ---------------- kernel 1: x2 = x*(nw+1)+nb; h = LN(x2@W) via MFMA;
// writes h_lnB (bf16 row-major) and hTt: element (b,n,d) at
// ((b*128 + n/32)*128 + d)*32 + (n&31) shorts.
__global__ __launch_bounds__(256) void k1_prep(
    const float* __restrict__ x, const U16* __restrict__ WT,
    const float* __restrict__ nw, const float* __restrict__ nb,
    const float* __restrict__ gamma, const float* __restrict__ beta,
    U16* __restrict__ h_lnB, U16* __restrict__ hTt)
{
  __shared__ U16 lds[16384];                 // 32 KB: WT (swizzled), later hb[64][128]
  const int tid = threadIdx.x;
  const int lane = tid & 63, w = tid >> 6;
  const int l15 = lane & 15, grp = lane >> 4;

  #pragma unroll
  for (int q = 0; q < 8; ++q){
    int cid = q*256 + tid;
    int dp = cid >> 4, c = cid & 15;
    *reinterpret_cast<int4*>(lds + dp*128 + ((c*8) ^ ((dp&15)<<3))) =
        *reinterpret_cast<const int4*>(WT + cid*8);
  }
  __syncthreads();

  const int rA = blockIdx.x*64 + w*16 + l15;
  const int nA = rA & 4095;
  const float wgt = nw[nA] + 1.0f, bia = nb[nA];
  const float* xr = x + (size_t)rA*DD;

  f32x4v acc[8] = {};
  #pragma unroll
  for (int ks = 0; ks < 4; ++ks){
    int d8 = ks*32 + grp*8;
    float4 xa = *reinterpret_cast<const float4*>(xr + d8);
    float4 xb = *reinterpret_cast<const float4*>(xr + d8 + 4);
    bfrag8 af;
    af[0] = (short)f2bf(xa.x*wgt + bia);
    af[1] = (short)f2bf(xa.y*wgt + bia);
    af[2] = (short)f2bf(xa.z*wgt + bia);
    af[3] = (short)f2bf(xa.w*wgt + bia);
    af[4] = (short)f2bf(xb.x*wgt + bia);
    af[5] = (short)f2bf(xb.y*wgt + bia);
    af[6] = (short)f2bf(xb.z*wgt + bia);
    af[7] = (short)f2bf(xb.w*wgt + bia);
    #pragma unroll
    for (int nf = 0; nf < 8; ++nf){
      int dp = nf*16 + l15;
      bfrag8 bf = *reinterpret_cast<const bfrag8*>(
          lds + dp*128 + ((((ks*4 + grp)*8)) ^ ((dp&15)<<3)));
      acc[nf] = __builtin_amdgcn_mfma_f32_16x16x32_bf16(af, bf, acc[nf], 0, 0, 0);
    }
  }

  float gc[8], bc[8];
  #pragma unroll
  for (int nf = 0; nf < 8; ++nf){
    int col = nf*16 + l15;
    gc[nf] = gamma[col]; bc[nf] = beta[col];
  }

  // C/D layout: col = lane&15, row = (lane>>4)*4 + r (m89-verified)
  const int rCb = blockIdx.x*64 + w*16 + grp*4;
  #pragma unroll
  for (int r = 0; r < 4; ++r){
    float s = 0.f, qq = 0.f;
    #pragma unroll
    for (int nf = 0; nf < 8; ++nf){ float v = acc[nf][r]; s += v; qq += v*v; }
    #pragma unroll
    for (int m = 1; m < 16; m <<= 1){ s += __shfl_xor(s, m); qq += __shfl_xor(qq, m); }
    float mu = s * 0.0078125f;
    float var = fmaxf(qq*0.0078125f - mu*mu, 0.f);
    float rstd = rsqrtf(var + 1e-5f);
    const int rC = rCb + r;
    #pragma unroll
    for (int nf = 0; nf < 8; ++nf){
      float hn = (acc[nf][r] - mu)*rstd*gc[nf] + bc[nf];
      acc[nf][r] = hn;
      h_lnB[(size_t)rC*DD + nf*16 + l15] = f2bf(hn);
    }
  }

  __syncthreads();   // WT no longer needed; reuse LDS as hb[64 n][128 d]
  #pragma unroll
  for (int r = 0; r < 4; ++r)
    #pragma unroll
    for (int nf = 0; nf < 8; ++nf)
      lds[(w*16 + grp*4 + r)*128 + nf*16 + l15] = f2bf(acc[nf][r]);
  __syncthreads();

  {
    const int r0 = blockIdx.x*64;
    const int bB = r0 >> 12;
    const int nt0 = (r0 & 4095) >> 5;
    U16* dstt = hTt + ((size_t)(bB*128 + nt0)*128)*32;
    const int h2 = tid >> 7, d = tid & 127;
    #pragma unroll
    for (int g = 0; g < 4; ++g){
      bfrag8 v;
      #pragma unroll
      for (int e = 0; e < 8; ++e)
        v[e] = (short)lds[(h2*32 + g*8 + e)*128 + d];
      *reinterpret_cast<bfrag8*>(dstt + ((size_t)(h2*128 + d))*32 + g*8) = v;
    }
  }
}

// ---------------- kernel 2: S = (1-adj)@h direct-to-register GEMM ----------------
// 1024 thr, 16 waves = 2 M-halves x 8 K-eighths; wave = 32 rows x 128 cols ->
// acc[2][8] = 64 regs -> 4 waves/SIMD (TLP covers L2 latency; no reg prefetch).
// M-sibling waves load identical B-frags (L1 hit). No barriers in main loop.
__global__ __launch_bounds__(1024, 4) void k2_main(
    const U32* __restrict__ adjbT, const U16* __restrict__ hTt,
    const U16* __restrict__ h_lnB, float* __restrict__ out)
{
  __shared__ U16 part[65536];                // 128 KB: 16 regions x [32 r][128 c] bf16
  const int tid = threadIdx.x;
  const int lane = tid & 63, w = tid >> 6;   // 16 waves
  const int mh = w >> 3, kq = w & 7;         // M-half, K-eighth
  const int l15 = lane & 15, grp = lane >> 4;
  const int bid = blockIdx.x;
  const int xcd = bid & 7;
  const int b = xcd >> 1;                    // batch pinned to XCD pair
  const int iblk = (((bid >> 3) << 1) | (xcd & 1)) * 64;
  const float CMASK = 0.2f * -9.0e15f;       // leaky(MASK_VAL), exact

  // transposed adj bits: word (g = kq*16+s) for rows iblk+mh*32+{l15, 16+l15}
  const U32* ar0 = adjbT + (size_t)(kq*16)*4096 + iblk + mh*32 + l15;
  const U32* ar1 = ar0 + 16;

  // B-fragment base: tile (b*128 + kq*16 + s), lane offset l15*32 + grp*8 shorts;
  // nf stride 512 shorts; s stride 4096 shorts.
  const U16* bp = hTt + ((size_t)(b*128 + kq*16)*128)*32 + l15*32 + grp*8;

  f32x4v acc[2][8] = {};

  #pragma unroll
  for (int s = 0; s < 16; ++s){
    const U16* q = bp + (size_t)s*4096;
    bfrag8 F0 = *reinterpret_cast<const bfrag8*>(q);
    bfrag8 F1 = *reinterpret_cast<const bfrag8*>(q + 512);
    bfrag8 F2 = *reinterpret_cast<const bfrag8*>(q + 1024);
    bfrag8 F3 = *reinterpret_cast<const bfrag8*>(q + 1536);
    bfrag8 F4 = *reinterpret_cast<const bfrag8*>(q + 2048);
    bfrag8 F5 = *reinterpret_cast<const bfrag8*>(q + 2560);
    bfrag8 F6 = *reinterpret_cast<const bfrag8*>(q + 3072);
    bfrag8 F7 = *reinterpret_cast<const bfrag8*>(q + 3584);
    const U32 w0 = ar0[(size_t)s*4096];
    const U32 w1 = ar1[(size_t)s*4096];
    bfrag8 a0 = afragb(w0 >> (grp*8));
    bfrag8 a1 = afragb(w1 >> (grp*8));
    acc[0][0] = __builtin_amdgcn_mfma_f32_16x16x32_bf16(a0, F0, acc[0][0], 0,0,0);
    acc[1][0] = __builtin_amdgcn_mfma_f32_16x16x32_bf16(a1, F0, acc[1][0], 0,0,0);
    acc[0][1] = __builtin_amdgcn_mfma_f32_16x16x32_bf16(a0, F1, acc[0][1], 0,0,0);
    acc[1][1] = __builtin_amdgcn_mfma_f32_16x16x32_bf16(a1, F1, acc[1][1], 0,0,0);
    acc[0][2] = __builtin_amdgcn_mfma_f32_16x16x32_bf16(a0, F2, acc[0][2], 0,0,0);
    acc[1][2] = __builtin_amdgcn_mfma_f32_16x16x32_bf16(a1, F2, acc[1][2], 0,0,0);
    acc[0][3] = __builtin_amdgcn_mfma_f32_16x16x32_bf16(a0, F3, acc[0][3], 0,0,0);
    acc[1][3] = __builtin_amdgcn_mfma_f32_16x16x32_bf16(a1, F3, acc[1][3], 0,0,0);
    acc[0][4] = __builtin_amdgcn_mfma_f32_16x16x32_bf16(a0, F4, acc[0][4], 0,0,0);
    acc[1][4] = __builtin_amdgcn_mfma_f32_16x16x32_bf16(a1, F4, acc[1][4], 0,0,0);
    acc[0][5] = __builtin_amdgcn_mfma_f32_16x16x32_bf16(a0, F5, acc[0][5], 0,0,0);
    acc[1][5] = __builtin_amdgcn_mfma_f32_16x16x32_bf16(a1, F5, acc[1][5], 0,0,0);
    acc[0][6] = __builtin_amdgcn_mfma_f32_16x16x32_bf16(a0, F6, acc[0][6], 0,0,0);
    acc[1][6] = __builtin_amdgcn_mfma_f32_16x16x32_bf16(a1, F6, acc[1][6], 0,0,0);
    acc[0][7] = __builtin_amdgcn_mfma_f32_16x16x32_bf16(a0, F7, acc[0][7], 0,0,0);
    acc[1][7] = __builtin_amdgcn_mfma_f32_16x16x32_bf16(a1, F7, acc[1][7], 0,0,0);
  }

  // ---- K-combine: bf16 partials in LDS, XOR-swizzled (2 lanes/bank = free) ----
  // region (mh*8 + kq): [32 rows][128 cols] bf16 = 8 KB
  U16* reg = part + (mh*8 + kq)*4096;
  #pragma unroll
  for (int f = 0; f < 2; ++f)
    #pragma unroll
    for (int nf = 0; nf < 8; ++nf){
      const int col = nf*16 + l15;
      #pragma unroll
      for (int r = 0; r < 4; ++r){
        const int lr = f*16 + grp*4 + r;
        reg[lr*128 + (col ^ (((lr>>2)&3)<<4))] = f2bf(acc[f][nf][r]);
      }
    }
  __syncthreads();

  // ---- epilogue: 4 rows per wave, sum 8 K-partials, elu + residual ----
  #pragma unroll
  for (int rr = 0; rr < 4; ++rr){
    const int row = w*4 + rr;                // 0..63
    const int mh2 = row >> 5, lr = row & 31;
    const int ci = lr*64 + (lane ^ (((lr>>2)&3)<<3));   // u32 idx within region
    float s0 = 0.f, s1 = 0.f;
    #pragma unroll
    for (int q = 0; q < 8; ++q){
      U32 p = reinterpret_cast<const U32*>(part)[(mh2*8 + q)*2048 + ci];
      s0 += bf2f(p & 0xffffu); s1 += bf2f(p >> 16);
    }
    const float h0 = CMASK * s0, h1 = CMASK * s1;
    const float e0 = h0 > 0.f ? h0 : __expf(h0) - 1.f;
    const float e1 = h1 > 0.f ? h1 : __expf(h1) - 1.f;
    const size_t o = ((size_t)b*NN + iblk + row)*DD + 2*lane;
    const U32 hl = *reinterpret_cast<const U32*>(h_lnB + o);
    float2 ov; ov.x = e0 + bf2f(hl & 0xffffu); ov.y = e1 + bf2f(hl >> 16);
    *reinterpret_cast<float2*>(out + o) = ov;
  }
}

extern "C" void kernel_launch(void* const* d_in, const int* in_sizes, int n_in,
                              void* d_out, int out_size, void* d_ws, size_t ws_size,
                              hipStream_t stream) {
  const float* x     = (const float*)d_in[0];
  const int*   adj   = (const int*)  d_in[1];
  const float* W     = (const float*)d_in[2];
  const float* nw    = (const float*)d_in[5];
  const float* nb    = (const float*)d_in[6];
  const float* gamma = (const float*)d_in[7];
  const float* beta  = (const float*)d_in[8];
  float* out = (float*)d_out;

  char* ws = (char*)d_ws;
  U16*   h_lnB = (U16*)(ws);                            // 4 MB
  U16*   hTt   = (U16*)(ws + 4*1024*1024);              // 4 MB
  U16*   WT    = (U16*)(ws + 8*1024*1024 + 16*1024);    // 32 KB
  U32*   adjbT = (U32*)(ws + 9*1024*1024);              // 2 MB

  k0_combo<<<dim3(2112), dim3(256), 0, stream>>>(adj, adjbT, W, WT);
  k1_prep <<<dim3(256),  dim3(256), 0, stream>>>(x, WT, nw, nb, gamma, beta,
                                                 h_lnB, hTt);
  k2_main <<<dim3(256),  dim3(1024), 0, stream>>>(adjbT, hTt, h_lnB, out);
}

// Round 14
// 51.722 us; speedup vs baseline: 1.1988x; 1.1988x over previous
//
#include <hip/hip_runtime.h>
#include <hip/hip_bf16.h>

typedef short bfrag8 __attribute__((ext_vector_type(8)));
typedef float f32x4v __attribute__((ext_vector_type(4)));
typedef unsigned short U16;
typedef unsigned int U32;

#define NN 4096
#define DD 128

static __device__ __forceinline__ U16 f2bf(float f){
  union { __hip_bfloat16 b; U16 u; } cv;
  cv.b = __float2bfloat16(f);
  return cv.u;
}

static __device__ __forceinline__ float bf2f(U32 u){
  union { float f; U32 u; } cv;
  cv.u = u << 16;
  return cv.f;
}

// A-fragment from inverted adjacency bits (low byte): bit=0 -> 1.0bf16, bit=1 -> 0
static __device__ __forceinline__ bfrag8 afragb(U32 y){
  bfrag8 a;
  #pragma unroll
  for (int e = 0; e < 8; ++e) a[e] = (y & (1u<<e)) ? (short)0 : (short)0x3F80;
  return a;
}

// ---------------- kernel 0: adj pack TRANSPOSED (blocks 0..2047) + W^T (2048..2111) --
// adjbT[g*4096 + row] bit j = adj[row][g*32 + j] != 0  (g = 32-col group).
__global__ __launch_bounds__(256) void k0_combo(const int* __restrict__ adj,
                                                U32* __restrict__ adjbT,
                                                const float* __restrict__ W,
                                                U16* __restrict__ WT){
  if (blockIdx.x >= 2048){
    int i = (blockIdx.x - 2048)*256 + threadIdx.x;  // i = d*128 + dp
    int d = i >> 7, dp = i & 127;
    WT[dp*128 + d] = f2bf(W[i]);
    return;
  }
  const int g   = blockIdx.x >> 4;                  // 0..127
  const int row = (blockIdx.x & 15)*256 + threadIdx.x;
  const int4* src = reinterpret_cast<const int4*>(adj + (size_t)row*NN + g*32);
  int4 v[8];
  #pragma unroll
  for (int c = 0; c < 8; ++c) v[c] = src[c];
  U32 m = 0;
  #pragma unroll
  for (int c = 0; c < 8; ++c){
    m |= (v[c].x != 0 ? 1u : 0u) << (c*4);
    m |= (v[c].y != 0 ? 2u : 0u) << (c*4);
    m |= (v[c].z != 0 ? 4u : 0u) << (c*4);
    m |= (v[c].w != 0 ? 8u : 0u) << (c*4);
  }
  adjbT[(size_t)g*4096 + row] = m;
}

// ---------------- kernel 1: x2 = x*(nw+1)+nb; h = LN(x2@W) via MFMA;
// x-slab staged coalesced into LDS (kills the 16-line A-gather), rotated chunks
// so fragment reads are <=2-way bank conflicts. Writes h_lnB + hTt (k2 layout).
__global__ __launch_bounds__(256) void k1_prep(
    const float* __restrict__ x, const U16* __restrict__ WT,
    const float* __restrict__ nw, const float* __restrict__ nb,
    const float* __restrict__ gamma, const float* __restrict__ beta,
    U16* __restrict__ h_lnB, U16* __restrict__ hTt)
{
  __shared__ char smem[65536];               // 64 KB: [0,32K) WT bf16; [32K,64K) x f32
  U16* lds = reinterpret_cast<U16*>(smem);
  float4* xs4 = reinterpret_cast<float4*>(smem + 32768);
  const int tid = threadIdx.x;
  const int lane = tid & 63, w = tid >> 6;
  const int l15 = lane & 15, grp = lane >> 4;

  // stage WT into LDS with XOR swizzle (proven R2 pattern)
  #pragma unroll
  for (int q = 0; q < 8; ++q){
    int cid = q*256 + tid;
    int dp = cid >> 4, c = cid & 15;
    *reinterpret_cast<int4*>(lds + dp*128 + ((c*8) ^ ((dp&15)<<3))) =
        *reinterpret_cast<const int4*>(WT + cid*8);
  }
  // stage x slab (64 rows x 128 f32, contiguous 32KB), rotated chunk placement:
  // logical (row, chunk c of 32) stored at row*32 + ((c + row*2) & 31)
  {
    const float4* xg = reinterpret_cast<const float4*>(x) + (size_t)blockIdx.x*2048;
    #pragma unroll
    for (int k = 0; k < 8; ++k){
      int g = k*256 + tid;                   // 0..2047
      int row = g >> 5, c = g & 31;
      xs4[row*32 + ((c + row*2) & 31)] = xg[g];
    }
  }
  __syncthreads();

  const int rA = blockIdx.x*64 + w*16 + l15;
  const int nA = rA & 4095;
  const float wgt = nw[nA] + 1.0f, bia = nb[nA];
  const int xrow = w*16 + l15;               // row within slab

  f32x4v acc[8] = {};
  #pragma unroll
  for (int ks = 0; ks < 4; ++ks){
    int c0 = ks*8 + grp*2;
    float4 xa = xs4[xrow*32 + ((c0     + xrow*2) & 31)];
    float4 xb = xs4[xrow*32 + ((c0 + 1 + xrow*2) & 31)];
    bfrag8 af;
    af[0] = (short)f2bf(xa.x*wgt + bia);
    af[1] = (short)f2bf(xa.y*wgt + bia);
    af[2] = (short)f2bf(xa.z*wgt + bia);
    af[3] = (short)f2bf(xa.w*wgt + bia);
    af[4] = (short)f2bf(xb.x*wgt + bia);
    af[5] = (short)f2bf(xb.y*wgt + bia);
    af[6] = (short)f2bf(xb.z*wgt + bia);
    af[7] = (short)f2bf(xb.w*wgt + bia);
    #pragma unroll
    for (int nf = 0; nf < 8; ++nf){
      int dp = nf*16 + l15;
      bfrag8 bf = *reinterpret_cast<const bfrag8*>(
          lds + dp*128 + ((((ks*4 + grp)*8)) ^ ((dp&15)<<3)));
      acc[nf] = __builtin_amdgcn_mfma_f32_16x16x32_bf16(af, bf, acc[nf], 0, 0, 0);
    }
  }

  float gc[8], bc[8];
  #pragma unroll
  for (int nf = 0; nf < 8; ++nf){
    int col = nf*16 + l15;
    gc[nf] = gamma[col]; bc[nf] = beta[col];
  }

  // C/D layout: col = lane&15, row = (lane>>4)*4 + r (m89-verified)
  const int rCb = blockIdx.x*64 + w*16 + grp*4;
  #pragma unroll
  for (int r = 0; r < 4; ++r){
    float s = 0.f, qq = 0.f;
    #pragma unroll
    for (int nf = 0; nf < 8; ++nf){ float v = acc[nf][r]; s += v; qq += v*v; }
    #pragma unroll
    for (int m = 1; m < 16; m <<= 1){ s += __shfl_xor(s, m); qq += __shfl_xor(qq, m); }
    float mu = s * 0.0078125f;
    float var = fmaxf(qq*0.0078125f - mu*mu, 0.f);
    float rstd = rsqrtf(var + 1e-5f);
    const int rC = rCb + r;
    #pragma unroll
    for (int nf = 0; nf < 8; ++nf){
      float hn = (acc[nf][r] - mu)*rstd*gc[nf] + bc[nf];
      acc[nf][r] = hn;
      h_lnB[(size_t)rC*DD + nf*16 + l15] = f2bf(hn);
    }
  }

  __syncthreads();   // WT no longer needed; reuse lds area as hb[64 n][128 d]
  #pragma unroll
  for (int r = 0; r < 4; ++r)
    #pragma unroll
    for (int nf = 0; nf < 8; ++nf)
      lds[(w*16 + grp*4 + r)*128 + nf*16 + l15] = f2bf(acc[nf][r]);
  __syncthreads();

  // write 2 hTt tiles (32 n each): element (b,n,d) at ((b*128+n/32)*128+d)*32+(n&31)
  {
    const int r0 = blockIdx.x*64;
    const int bB = r0 >> 12;
    const int nt0 = (r0 & 4095) >> 5;
    U16* dstt = hTt + ((size_t)(bB*128 + nt0)*128)*32;
    const int h2 = tid >> 7, d = tid & 127;
    #pragma unroll
    for (int g = 0; g < 4; ++g){
      bfrag8 v;
      #pragma unroll
      for (int e = 0; e < 8; ++e)
        v[e] = (short)lds[(h2*32 + g*8 + e)*128 + d];
      *reinterpret_cast<bfrag8*>(dstt + ((size_t)(h2*128 + d))*32 + g*8) = v;
    }
  }
}

// ---------------- kernel 2: S = (1-adj)@h direct-to-register GEMM ----------------
// The 51.7µs version verbatim: XCD-pinned batch, 8 waves = K-eighths, adjbT
// in-loop broadcasts, double-banked named-reg B prefetch, combine via LDS.
__global__ __launch_bounds__(512, 2) void k2_main(
    const U32* __restrict__ adjbT, const U16* __restrict__ hTt,
    const U16* __restrict__ h_lnB, float* __restrict__ out)
{
  __shared__ U16 part[65536];                // 128 KB: 8 regions x [64 r][128 c] bf16
  const int tid = threadIdx.x;
  const int lane = tid & 63, w = tid >> 6;   // w = K-eighth
  const int l15 = lane & 15, grp = lane >> 4;
  const int bid = blockIdx.x;
  const int xcd = bid & 7;
  const int b = xcd >> 1;                    // batch pinned to XCD pair
  const int iblk = (((bid >> 3) << 1) | (xcd & 1)) * 64;
  const float CMASK = 0.2f * -9.0e15f;       // leaky(MASK_VAL), exact

  // transposed adj bits: word (g = w*16+s) for rows iblk+f*16+l15 -> consecutive u32
  const U32* ar0 = adjbT + (size_t)(w*16)*4096 + iblk +      l15;
  const U32* ar1 = adjbT + (size_t)(w*16)*4096 + iblk + 16 + l15;
  const U32* ar2 = adjbT + (size_t)(w*16)*4096 + iblk + 32 + l15;
  const U32* ar3 = adjbT + (size_t)(w*16)*4096 + iblk + 48 + l15;

  // B-fragment base: tile (b*128 + w*16 + s), lane offset l15*32 + grp*8 shorts;
  // nf stride 512 shorts; s stride 4096 shorts. Wave's 8 loads/step = 1KB contig.
  const U16* bp = hTt + ((size_t)(b*128 + w*16)*128)*32 + l15*32 + grp*8;

  f32x4v acc[4][8] = {};

#define LOADB(P0,P1,P2,P3,P4,P5,P6,P7, S) do { \
    const U16* _q = bp + (size_t)(S)*4096; \
    P0 = *reinterpret_cast<const bfrag8*>(_q);        \
    P1 = *reinterpret_cast<const bfrag8*>(_q + 512);  \
    P2 = *reinterpret_cast<const bfrag8*>(_q + 1024); \
    P3 = *reinterpret_cast<const bfrag8*>(_q + 1536); \
    P4 = *reinterpret_cast<const bfrag8*>(_q + 2048); \
    P5 = *reinterpret_cast<const bfrag8*>(_q + 2560); \
    P6 = *reinterpret_cast<const bfrag8*>(_q + 3072); \
    P7 = *reinterpret_cast<const bfrag8*>(_q + 3584); } while(0)

#define COLM(CF, NF) do { \
    acc[0][NF] = __builtin_amdgcn_mfma_f32_16x16x32_bf16(a0, CF, acc[0][NF], 0,0,0); \
    acc[1][NF] = __builtin_amdgcn_mfma_f32_16x16x32_bf16(a1, CF, acc[1][NF], 0,0,0); \
    acc[2][NF] = __builtin_amdgcn_mfma_f32_16x16x32_bf16(a2, CF, acc[2][NF], 0,0,0); \
    acc[3][NF] = __builtin_amdgcn_mfma_f32_16x16x32_bf16(a3, CF, acc[3][NF], 0,0,0); } while(0)

#define COMPUTE(P0,P1,P2,P3,P4,P5,P6,P7, W0,W1,W2,W3) do { \
    bfrag8 a0 = afragb((W0) >> (grp*8)), a1 = afragb((W1) >> (grp*8)); \
    bfrag8 a2 = afragb((W2) >> (grp*8)), a3 = afragb((W3) >> (grp*8)); \
    COLM(P0, 0); COLM(P1, 1); COLM(P2, 2); COLM(P3, 3); \
    COLM(P4, 4); COLM(P5, 5); COLM(P6, 6); COLM(P7, 7); } while(0)

  bfrag8 A0,A1,A2,A3,A4,A5,A6,A7, B0,B1,B2,B3,B4,B5,B6,B7;
  U32 wa0,wa1,wa2,wa3, wb0,wb1,wb2,wb3;

  LOADB(A0,A1,A2,A3,A4,A5,A6,A7, 0);
  wa0 = ar0[0]; wa1 = ar1[0]; wa2 = ar2[0]; wa3 = ar3[0];

  #pragma unroll 1
  for (int it = 0; it < 8; ++it){
    const int s = it*2;
    LOADB(B0,B1,B2,B3,B4,B5,B6,B7, s+1);
    wb0 = ar0[(size_t)(s+1)*4096]; wb1 = ar1[(size_t)(s+1)*4096];
    wb2 = ar2[(size_t)(s+1)*4096]; wb3 = ar3[(size_t)(s+1)*4096];
    COMPUTE(A0,A1,A2,A3,A4,A5,A6,A7, wa0,wa1,wa2,wa3);
    LOADB(A0,A1,A2,A3,A4,A5,A6,A7, s+2);     // s+2==16 on last iter: reads pad
    wa0 = ar0[(size_t)(s+2)*4096]; wa1 = ar1[(size_t)(s+2)*4096];
    wa2 = ar2[(size_t)(s+2)*4096]; wa3 = ar3[(size_t)(s+2)*4096];
    COMPUTE(B0,B1,B2,B3,B4,B5,B6,B7, wb0,wb1,wb2,wb3);
  }

  // ---- K-combine: bf16 partials in LDS, XOR-swizzled (2 lanes/bank = free) ----
  U16* reg = part + w*8192;
  #pragma unroll
  for (int f = 0; f < 4; ++f)
    #pragma unroll
    for (int nf = 0; nf < 8; ++nf){
      const int col = nf*16 + l15;
      #pragma unroll
      for (int r = 0; r < 4; ++r){
        const int lr = f*16 + grp*4 + r;
        reg[lr*128 + (col ^ (((lr>>2)&3)<<4))] = f2bf(acc[f][nf][r]);
      }
    }
  __syncthreads();

  #pragma unroll
  for (int rr = 0; rr < 8; ++rr){
    const int row = w*8 + rr;
    const int ci = row*64 + (lane ^ (((row>>2)&3)<<3));   // u32 index (row-const XOR)
    float s0 = 0.f, s1 = 0.f;
    #pragma unroll
    for (int q = 0; q < 8; ++q){
      U32 p = reinterpret_cast<const U32*>(part)[q*4096 + ci];
      s0 += bf2f(p & 0xffffu); s1 += bf2f(p >> 16);
    }
    const float h0 = CMASK * s0, h1 = CMASK * s1;
    const float e0 = h0 > 0.f ? h0 : __expf(h0) - 1.f;
    const float e1 = h1 > 0.f ? h1 : __expf(h1) - 1.f;
    const size_t o = ((size_t)b*NN + iblk + row)*DD + 2*lane;
    const U32 hl = *reinterpret_cast<const U32*>(h_lnB + o);
    float2 ov; ov.x = e0 + bf2f(hl & 0xffffu); ov.y = e1 + bf2f(hl >> 16);
    *reinterpret_cast<float2*>(out + o) = ov;
  }
#undef COLM
#undef COMPUTE
#undef LOADB
}

extern "C" void kernel_launch(void* const* d_in, const int* in_sizes, int n_in,
                              void* d_out, int out_size, void* d_ws, size_t ws_size,
                              hipStream_t stream) {
  const float* x     = (const float*)d_in[0];
  const int*   adj   = (const int*)  d_in[1];
  const float* W     = (const float*)d_in[2];
  const float* nw    = (const float*)d_in[5];
  const float* nb    = (const float*)d_in[6];
  const float* gamma = (const float*)d_in[7];
  const float* beta  = (const float*)d_in[8];
  float* out = (float*)d_out;

  char* ws = (char*)d_ws;
  U16*   h_lnB = (U16*)(ws);                            // 4 MB
  U16*   hTt   = (U16*)(ws + 4*1024*1024);              // 4 MB + pad
  U16*   WT    = (U16*)(ws + 8*1024*1024 + 16*1024);    // 32 KB
  U32*   adjbT = (U32*)(ws + 9*1024*1024);              // 2 MB + pad

  k0_combo<<<dim3(2112), dim3(256), 0, stream>>>(adj, adjbT, W, WT);
  k1_prep <<<dim3(256),  dim3(256), 0, stream>>>(x, WT, nw, nb, gamma, beta,
                                                 h_lnB, hTt);
  k2_main <<<dim3(256),  dim3(512), 0, stream>>>(adjbT, hTt, h_lnB, out);
}

// Round 15
// 43.349 us; speedup vs baseline: 1.4303x; 1.1931x over previous
//
#include <hip/hip_runtime.h>
#include <hip/hip_bf16.h>

typedef short bfrag8 __attribute__((ext_vector_type(8)));
typedef float f32x4v __attribute__((ext_vector_type(4)));
typedef int i32x4 __attribute__((ext_vector_type(4)));
typedef unsigned short U16;
typedef unsigned int U32;

#define NN 4096
#define DD 128

static __device__ __forceinline__ U16 f2bf(float f){
  union { __hip_bfloat16 b; U16 u; } cv;
  cv.b = __float2bfloat16(f);
  return cv.u;
}

static __device__ __forceinline__ float bf2f(U32 u){
  union { float f; U32 u; } cv;
  cv.u = u << 16;
  return cv.f;
}

// i8 A-fragment (4 regs, 16 bytes of 0/1) from INVERTED adjacency bits.
// byte c of reg r = bit (r*4+c) of this lane's 16-bit window.
static __device__ __forceinline__ i32x4 afragi8(U32 wl, U32 wh, int grp, U32 mul){
  U32 y = ((grp & 2) ? wh : wl) >> ((grp & 1) * 16);
  i32x4 a;
  a[0] = (int)((((y >>  0) & 0xFu) * mul) & 0x01010101u);
  a[1] = (int)((((y >>  4) & 0xFu) * mul) & 0x01010101u);
  a[2] = (int)((((y >>  8) & 0xFu) * mul) & 0x01010101u);
  a[3] = (int)((((y >> 12) & 0xFu) * mul) & 0x01010101u);
  return a;
}

// ---------------- kernel 0: adj pack TRANSPOSED+INVERTED (0..2047) + W^T ----------
// adjbT[g*4096 + row] bit j = (adj[row][g*32+j] == 0)   <-- INVERTED (mask value)
__global__ __launch_bounds__(256) void k0_combo(const int* __restrict__ adj,
                                                U32* __restrict__ adjbT,
                                                const float* __restrict__ W,
                                                U16* __restrict__ WT){
  if (blockIdx.x >= 2048){
    int i = (blockIdx.x - 2048)*256 + threadIdx.x;  // i = d*128 + dp
    int d = i >> 7, dp = i & 127;
    WT[dp*128 + d] = f2bf(W[i]);
    return;
  }
  const int g   = blockIdx.x >> 4;                  // 0..127
  const int row = (blockIdx.x & 15)*256 + threadIdx.x;
  const int4* src = reinterpret_cast<const int4*>(adj + (size_t)row*NN + g*32);
  int4 v[8];
  #pragma unroll
  for (int c = 0; c < 8; ++c) v[c] = src[c];
  U32 m = 0;
  #pragma unroll
  for (int c = 0; c < 8; ++c){
    m |= (v[c].x != 0 ? 0u : 1u) << (c*4);
    m |= (v[c].y != 0 ? 0u : 2u) << (c*4);
    m |= (v[c].z != 0 ? 0u : 4u) << (c*4);
    m |= (v[c].w != 0 ? 0u : 8u) << (c*4);
  }
  adjbT[(size_t)g*4096 + row] = m;
}

// ---------------- kernel 1: x2 = x*(nw+1)+nb; h = LN(x2@W) via MFMA;
// writes h_lnB (bf16 row-major) and hTi8: h quantized i8 (scale 32), tiled:
// byte (b, n, d) at ((b*64 + n/64)*128 + d)*64 + (n&63) -> a wave's 8 fragment
// loads per 64-n tile are 1KB contiguous each.
__global__ __launch_bounds__(256) void k1_prep(
    const float* __restrict__ x, const U16* __restrict__ WT,
    const float* __restrict__ nw, const float* __restrict__ nb,
    const float* __restrict__ gamma, const float* __restrict__ beta,
    U16* __restrict__ h_lnB, char* __restrict__ hTi8)
{
  __shared__ char smem[65536];               // 64 KB: [0,32K) WT bf16; [32K,64K) x f32
  U16* lds = reinterpret_cast<U16*>(smem);
  float4* xs4 = reinterpret_cast<float4*>(smem + 32768);
  const int tid = threadIdx.x;
  const int lane = tid & 63, w = tid >> 6;
  const int l15 = lane & 15, grp = lane >> 4;

  // stage WT into LDS with XOR swizzle (proven R2 pattern)
  #pragma unroll
  for (int q = 0; q < 8; ++q){
    int cid = q*256 + tid;
    int dp = cid >> 4, c = cid & 15;
    *reinterpret_cast<int4*>(lds + dp*128 + ((c*8) ^ ((dp&15)<<3))) =
        *reinterpret_cast<const int4*>(WT + cid*8);
  }
  // stage x slab (64 rows x 128 f32, contiguous 32KB), rotated chunk placement
  {
    const float4* xg = reinterpret_cast<const float4*>(x) + (size_t)blockIdx.x*2048;
    #pragma unroll
    for (int k = 0; k < 8; ++k){
      int g = k*256 + tid;                   // 0..2047
      int row = g >> 5, c = g & 31;
      xs4[row*32 + ((c + row*2) & 31)] = xg[g];
    }
  }
  __syncthreads();

  const int rA = blockIdx.x*64 + w*16 + l15;
  const int nA = rA & 4095;
  const float wgt = nw[nA] + 1.0f, bia = nb[nA];
  const int xrow = w*16 + l15;               // row within slab

  f32x4v acc[8] = {};
  #pragma unroll
  for (int ks = 0; ks < 4; ++ks){
    int c0 = ks*8 + grp*2;
    float4 xa = xs4[xrow*32 + ((c0     + xrow*2) & 31)];
    float4 xb = xs4[xrow*32 + ((c0 + 1 + xrow*2) & 31)];
    bfrag8 af;
    af[0] = (short)f2bf(xa.x*wgt + bia);
    af[1] = (short)f2bf(xa.y*wgt + bia);
    af[2] = (short)f2bf(xa.z*wgt + bia);
    af[3] = (short)f2bf(xa.w*wgt + bia);
    af[4] = (short)f2bf(xb.x*wgt + bia);
    af[5] = (short)f2bf(xb.y*wgt + bia);
    af[6] = (short)f2bf(xb.z*wgt + bia);
    af[7] = (short)f2bf(xb.w*wgt + bia);
    #pragma unroll
    for (int nf = 0; nf < 8; ++nf){
      int dp = nf*16 + l15;
      bfrag8 bf = *reinterpret_cast<const bfrag8*>(
          lds + dp*128 + ((((ks*4 + grp)*8)) ^ ((dp&15)<<3)));
      acc[nf] = __builtin_amdgcn_mfma_f32_16x16x32_bf16(af, bf, acc[nf], 0, 0, 0);
    }
  }

  float gc[8], bc[8];
  #pragma unroll
  for (int nf = 0; nf < 8; ++nf){
    int col = nf*16 + l15;
    gc[nf] = gamma[col]; bc[nf] = beta[col];
  }

  // C/D layout: col = lane&15, row = (lane>>4)*4 + r (m89-verified)
  const int rCb = blockIdx.x*64 + w*16 + grp*4;
  #pragma unroll
  for (int r = 0; r < 4; ++r){
    float s = 0.f, qq = 0.f;
    #pragma unroll
    for (int nf = 0; nf < 8; ++nf){ float v = acc[nf][r]; s += v; qq += v*v; }
    #pragma unroll
    for (int m = 1; m < 16; m <<= 1){ s += __shfl_xor(s, m); qq += __shfl_xor(qq, m); }
    float mu = s * 0.0078125f;
    float var = fmaxf(qq*0.0078125f - mu*mu, 0.f);
    float rstd = rsqrtf(var + 1e-5f);
    const int rC = rCb + r;
    #pragma unroll
    for (int nf = 0; nf < 8; ++nf){
      float hn = (acc[nf][r] - mu)*rstd*gc[nf] + bc[nf];
      acc[nf][r] = hn;
      h_lnB[(size_t)rC*DD + nf*16 + l15] = f2bf(hn);
    }
  }

  __syncthreads();   // WT no longer needed; reuse lds area as hb[64 n][128 d] bf16
  #pragma unroll
  for (int r = 0; r < 4; ++r)
    #pragma unroll
    for (int nf = 0; nf < 8; ++nf)
      lds[(w*16 + grp*4 + r)*128 + nf*16 + l15] = f2bf(acc[nf][r]);
  __syncthreads();

  // write the block's 64-n i8 tile: thread = (half = tid>>7, d = tid&127),
  // 32 bytes (n = half*32..+32) at ((bB*64+nt)*128 + d)*64 + half*32.
  {
    const int r0 = blockIdx.x*64;
    const int bB = r0 >> 12;
    const int nt = (r0 & 4095) >> 6;
    char* dstt = hTi8 + (((size_t)(bB*64 + nt)*128) << 6);
    const int d = tid & 127, half = tid >> 7;
    int4 pa, pb;
    int pk[8];
    #pragma unroll
    for (int j = 0; j < 8; ++j){
      U32 word = 0;
      #pragma unroll
      for (int c = 0; c < 4; ++c){
        float v = bf2f((U32)lds[(half*32 + j*4 + c)*128 + d]);
        float qf = fminf(fmaxf(rintf(v*32.f), -127.f), 127.f);
        int qi = (int)qf;
        word |= ((U32)(qi & 0xFF)) << (c*8);
      }
      pk[j] = (int)word;
    }
    pa.x = pk[0]; pa.y = pk[1]; pa.z = pk[2]; pa.w = pk[3];
    pb.x = pk[4]; pb.y = pk[5]; pb.z = pk[6]; pb.w = pk[7];
    *reinterpret_cast<int4*>(dstt + (size_t)d*64 + half*32)      = pa;
    *reinterpret_cast<int4*>(dstt + (size_t)d*64 + half*32 + 16) = pb;
  }
}

// ---------------- kernel 2: S = mask@h via i8 MFMA (K=64), exact i32 combine ----
// 8 waves = K-eighths (8 tiles of 64 n each), 64 rows, direct-to-register B,
// 2-banked named-reg prefetch, no main-loop barriers. XCD-pinned batch.
__global__ __launch_bounds__(512, 2) void k2_main(
    const U32* __restrict__ adjbT, const char* __restrict__ hTi8,
    const U16* __restrict__ h_lnB, float* __restrict__ out)
{
  __shared__ int part[32768];                // 128 KB: 4 regions x [64 r][128 c] i32
  const int tid = threadIdx.x;
  const int lane = tid & 63, w = tid >> 6;   // w = K-eighth
  const int l15 = lane & 15, grp = lane >> 4;
  const int bid = blockIdx.x;
  const int xcd = bid & 7;
  const int b = xcd >> 1;                    // batch pinned to XCD pair
  const int iblk = (((bid >> 3) << 1) | (xcd & 1)) * 64;
  const float CM2 = 0.2f * -9.0e15f / 32.0f; // leaky(MASK_VAL) / quant scale
  const U32 MUL = 0x00204081u;

  // inverted adj bits (transposed): words g = w*16 + 2s (+1) for row f*16+l15
  const U32* ar0 = adjbT + (size_t)(w*16)*4096 + iblk +      l15;
  const U32* ar1 = adjbT + (size_t)(w*16)*4096 + iblk + 16 + l15;
  const U32* ar2 = adjbT + (size_t)(w*16)*4096 + iblk + 32 + l15;
  const U32* ar3 = adjbT + (size_t)(w*16)*4096 + iblk + 48 + l15;

  // B base: tile (b*64 + w*8 + s); lane offset l15*64 + grp*16 bytes;
  // nf stride 1024 B; s stride 8192 B. Wave's 8 loads/step = 1KB contig each.
  const char* bp = hTi8 + (((size_t)(b*64 + w*8)*128) << 6) + l15*64 + grp*16;

  i32x4 acc[4][8] = {};

#define LOADB(P0,P1,P2,P3,P4,P5,P6,P7, S) do { \
    const char* _q = bp + (size_t)(S)*8192; \
    P0 = *reinterpret_cast<const i32x4*>(_q);        \
    P1 = *reinterpret_cast<const i32x4*>(_q + 1024); \
    P2 = *reinterpret_cast<const i32x4*>(_q + 2048); \
    P3 = *reinterpret_cast<const i32x4*>(_q + 3072); \
    P4 = *reinterpret_cast<const i32x4*>(_q + 4096); \
    P5 = *reinterpret_cast<const i32x4*>(_q + 5120); \
    P6 = *reinterpret_cast<const i32x4*>(_q + 6144); \
    P7 = *reinterpret_cast<const i32x4*>(_q + 7168); } while(0)

#define LOADW(L0,H0,L1,H1,L2,H2,L3,H3, S) do { \
    L0 = ar0[(size_t)(2*(S))*4096];   H0 = ar0[(size_t)(2*(S)+1)*4096]; \
    L1 = ar1[(size_t)(2*(S))*4096];   H1 = ar1[(size_t)(2*(S)+1)*4096]; \
    L2 = ar2[(size_t)(2*(S))*4096];   H2 = ar2[(size_t)(2*(S)+1)*4096]; \
    L3 = ar3[(size_t)(2*(S))*4096];   H3 = ar3[(size_t)(2*(S)+1)*4096]; } while(0)

#define COLM(CF, NF) do { \
    acc[0][NF] = __builtin_amdgcn_mfma_i32_16x16x64_i8(a0, CF, acc[0][NF], 0,0,0); \
    acc[1][NF] = __builtin_amdgcn_mfma_i32_16x16x64_i8(a1, CF, acc[1][NF], 0,0,0); \
    acc[2][NF] = __builtin_amdgcn_mfma_i32_16x16x64_i8(a2, CF, acc[2][NF], 0,0,0); \
    acc[3][NF] = __builtin_amdgcn_mfma_i32_16x16x64_i8(a3, CF, acc[3][NF], 0,0,0); } while(0)

#define COMPUTE(P0,P1,P2,P3,P4,P5,P6,P7, L0,H0,L1,H1,L2,H2,L3,H3) do { \
    i32x4 a0 = afragi8(L0, H0, grp, MUL); \
    i32x4 a1 = afragi8(L1, H1, grp, MUL); \
    i32x4 a2 = afragi8(L2, H2, grp, MUL); \
    i32x4 a3 = afragi8(L3, H3, grp, MUL); \
    COLM(P0, 0); COLM(P1, 1); COLM(P2, 2); COLM(P3, 3); \
    COLM(P4, 4); COLM(P5, 5); COLM(P6, 6); COLM(P7, 7); } while(0)

  i32x4 A0,A1,A2,A3,A4,A5,A6,A7, B0,B1,B2,B3,B4,B5,B6,B7;
  U32 aL0,aH0,aL1,aH1,aL2,aH2,aL3,aH3;
  U32 bL0,bH0,bL1,bH1,bL2,bH2,bL3,bH3;

  LOADB(A0,A1,A2,A3,A4,A5,A6,A7, 0);
  LOADW(aL0,aH0,aL1,aH1,aL2,aH2,aL3,aH3, 0);

  #pragma unroll 1
  for (int it = 0; it < 4; ++it){
    const int s = it*2;
    LOADB(B0,B1,B2,B3,B4,B5,B6,B7, s+1);
    LOADW(bL0,bH0,bL1,bH1,bL2,bH2,bL3,bH3, s+1);
    COMPUTE(A0,A1,A2,A3,A4,A5,A6,A7, aL0,aH0,aL1,aH1,aL2,aH2,aL3,aH3);
    LOADB(A0,A1,A2,A3,A4,A5,A6,A7, s+2);     // s+2==8 on last iter: reads pad
    LOADW(aL0,aH0,aL1,aH1,aL2,aH2,aL3,aH3, s+2);
    COMPUTE(B0,B1,B2,B3,B4,B5,B6,B7, bL0,bH0,bL1,bH1,bL2,bH2,bL3,bH3);
  }

  // ---- exact i32 K-combine: 4 regions; waves 0-3 write, 4-7 RMW-add ----
  {
    int* reg = part + (w & 3)*8192;          // region = [64 r][128 c] i32
    if (w < 4){
      #pragma unroll
      for (int f = 0; f < 4; ++f)
        #pragma unroll
        for (int nf = 0; nf < 8; ++nf){
          const int col = nf*16 + l15;
          #pragma unroll
          for (int r = 0; r < 4; ++r){
            const int lr = f*16 + grp*4 + r;
            reg[lr*128 + (col ^ (((lr>>2)&3)<<4))] = acc[f][nf][r];
          }
        }
    }
    __syncthreads();
    if (w >= 4){
      #pragma unroll
      for (int f = 0; f < 4; ++f)
        #pragma unroll
        for (int nf = 0; nf < 8; ++nf){
          const int col = nf*16 + l15;
          #pragma unroll
          for (int r = 0; r < 4; ++r){
            const int lr = f*16 + grp*4 + r;
            const int idx = lr*128 + (col ^ (((lr>>2)&3)<<4));
            reg[idx] += acc[f][nf][r];
          }
        }
    }
    __syncthreads();
  }

  // ---- epilogue: 8 rows/wave, sum 4 regions, elu + residual ----
  #pragma unroll
  for (int rr = 0; rr < 8; ++rr){
    const int row = w*8 + rr;
    const int sw = ((row>>2)&3)<<4;
    const int idx = row*128 + ((2*lane) ^ sw);  // pair-safe: sw has no bit0
    int s0 = 0, s1 = 0;
    #pragma unroll
    for (int q = 0; q < 4; ++q){
      int2 v = *reinterpret_cast<const int2*>(part + q*8192 + idx);
      s0 += v.x; s1 += v.y;
    }
    const float h0 = CM2 * (float)s0, h1 = CM2 * (float)s1;
    const float e0 = h0 > 0.f ? h0 : __expf(h0) - 1.f;
    const float e1 = h1 > 0.f ? h1 : __expf(h1) - 1.f;
    const size_t o = ((size_t)b*NN + iblk + row)*DD + 2*lane;
    const U32 hl = *reinterpret_cast<const U32*>(h_lnB + o);
    float2 ov; ov.x = e0 + bf2f(hl & 0xffffu); ov.y = e1 + bf2f(hl >> 16);
    *reinterpret_cast<float2*>(out + o) = ov;
  }
#undef COLM
#undef COMPUTE
#undef LOADW
#undef LOADB
}

extern "C" void kernel_launch(void* const* d_in, const int* in_sizes, int n_in,
                              void* d_out, int out_size, void* d_ws, size_t ws_size,
                              hipStream_t stream) {
  const float* x     = (const float*)d_in[0];
  const int*   adj   = (const int*)  d_in[1];
  const float* W     = (const float*)d_in[2];
  const float* nw    = (const float*)d_in[5];
  const float* nb    = (const float*)d_in[6];
  const float* gamma = (const float*)d_in[7];
  const float* beta  = (const float*)d_in[8];
  float* out = (float*)d_out;

  char* ws = (char*)d_ws;
  U16*  h_lnB = (U16*)(ws);                             // 4 MB
  char* hTi8  = (char*)(ws + 4*1024*1024);              // 2 MB + 16 KB pad
  U16*  WT    = (U16*)(ws + 6*1024*1024 + 64*1024);     // 32 KB
  U32*  adjbT = (U32*)(ws + 7*1024*1024);               // 2 MB + 64 KB pad

  k0_combo<<<dim3(2112), dim3(256), 0, stream>>>(adj, adjbT, W, WT);
  k1_prep <<<dim3(256),  dim3(256), 0, stream>>>(x, WT, nw, nb, gamma, beta,
                                                 h_lnB, hTi8);
  k2_main <<<dim3(256),  dim3(512), 0, stream>>>(adjbT, hTi8, h_lnB, out);
}

// Round 16
// 43.040 us; speedup vs baseline: 1.4406x; 1.0072x over previous
//
#include <hip/hip_runtime.h>
#include <hip/hip_bf16.h>

typedef short bfrag8 __attribute__((ext_vector_type(8)));
typedef float f32x4v __attribute__((ext_vector_type(4)));
typedef int i32x4 __attribute__((ext_vector_type(4)));
typedef unsigned short U16;
typedef unsigned int U32;

#define NN 4096
#define DD 128

static __device__ __forceinline__ U16 f2bf(float f){
  union { __hip_bfloat16 b; U16 u; } cv;
  cv.b = __float2bfloat16(f);
  return cv.u;
}

static __device__ __forceinline__ float bf2f(U32 u){
  union { float f; U32 u; } cv;
  cv.u = u << 16;
  return cv.f;
}

// i8 A-fragment (4 regs, 16 bytes of 0/1) from INVERTED adjacency bits.
static __device__ __forceinline__ i32x4 afragi8(U32 wl, U32 wh, int grp, U32 mul){
  U32 y = ((grp & 2) ? wh : wl) >> ((grp & 1) * 16);
  i32x4 a;
  a[0] = (int)((((y >>  0) & 0xFu) * mul) & 0x01010101u);
  a[1] = (int)((((y >>  4) & 0xFu) * mul) & 0x01010101u);
  a[2] = (int)((((y >>  8) & 0xFu) * mul) & 0x01010101u);
  a[3] = (int)((((y >> 12) & 0xFu) * mul) & 0x01010101u);
  return a;
}

// ---------------- kernel 0: adj pack TRANSPOSED+INVERTED (0..2047) + W^T ----------
__global__ __launch_bounds__(256) void k0_combo(const int* __restrict__ adj,
                                                U32* __restrict__ adjbT,
                                                const float* __restrict__ W,
                                                U16* __restrict__ WT){
  if (blockIdx.x >= 2048){
    int i = (blockIdx.x - 2048)*256 + threadIdx.x;  // i = d*128 + dp
    int d = i >> 7, dp = i & 127;
    WT[dp*128 + d] = f2bf(W[i]);
    return;
  }
  const int g   = blockIdx.x >> 4;                  // 0..127
  const int row = (blockIdx.x & 15)*256 + threadIdx.x;
  const int4* src = reinterpret_cast<const int4*>(adj + (size_t)row*NN + g*32);
  int4 v[8];
  #pragma unroll
  for (int c = 0; c < 8; ++c) v[c] = src[c];
  U32 m = 0;
  #pragma unroll
  for (int c = 0; c < 8; ++c){
    m |= (v[c].x != 0 ? 0u : 1u) << (c*4);
    m |= (v[c].y != 0 ? 0u : 2u) << (c*4);
    m |= (v[c].z != 0 ? 0u : 4u) << (c*4);
    m |= (v[c].w != 0 ? 0u : 8u) << (c*4);
  }
  adjbT[(size_t)g*4096 + row] = m;
}

// ---------------- kernel 1: 512 thr / 8 waves = 4 row-groups x 2 col-halves ------
// x2 = x*(nw+1)+nb; h = LN(x2@W); LN via cross-wave col-half exchange (1KB LDS).
// Writes h_lnB (bf16) + hTi8 (i8 scale 32, tiled ((b*64+nt)*128+d)*64+(n&63)).
__global__ __launch_bounds__(512) void k1_prep(
    const float* __restrict__ x, const U16* __restrict__ WT,
    const float* __restrict__ nw, const float* __restrict__ nb,
    const float* __restrict__ gamma, const float* __restrict__ beta,
    U16* __restrict__ h_lnB, char* __restrict__ hTi8)
{
  __shared__ char smem[66560];               // 32K WT | 32K x-slab | 1K LN exchange
  U16* lds = reinterpret_cast<U16*>(smem);
  float4* xs4 = reinterpret_cast<float4*>(smem + 32768);
  float2* lnx = reinterpret_cast<float2*>(smem + 65536);   // [2 ch][64 rows]
  const int tid = threadIdx.x;
  const int lane = tid & 63, w = tid >> 6;
  const int rh = w >> 1, ch = w & 1;         // row-group (16 rows), col-half (64)
  const int l15 = lane & 15, grp = lane >> 4;

  // stage WT (swizzled) + x-slab (rotated chunks), 512 threads
  #pragma unroll
  for (int q = 0; q < 4; ++q){
    int cid = q*512 + tid;
    int dp = cid >> 4, c = cid & 15;
    *reinterpret_cast<int4*>(lds + dp*128 + ((c*8) ^ ((dp&15)<<3))) =
        *reinterpret_cast<const int4*>(WT + cid*8);
  }
  {
    const float4* xg = reinterpret_cast<const float4*>(x) + (size_t)blockIdx.x*2048;
    #pragma unroll
    for (int k = 0; k < 4; ++k){
      int g = k*512 + tid;                   // 0..2047
      int row = g >> 5, c = g & 31;
      xs4[row*32 + ((c + row*2) & 31)] = xg[g];
    }
  }
  __syncthreads();

  const int rA = blockIdx.x*64 + rh*16 + l15;
  const int nA = rA & 4095;
  const float wgt = nw[nA] + 1.0f, bia = nb[nA];
  const int xrow = rh*16 + l15;              // row within slab

  f32x4v acc[4] = {};
  #pragma unroll
  for (int ks = 0; ks < 4; ++ks){
    int c0 = ks*8 + grp*2;
    float4 xa = xs4[xrow*32 + ((c0     + xrow*2) & 31)];
    float4 xb = xs4[xrow*32 + ((c0 + 1 + xrow*2) & 31)];
    bfrag8 af;
    af[0] = (short)f2bf(xa.x*wgt + bia);
    af[1] = (short)f2bf(xa.y*wgt + bia);
    af[2] = (short)f2bf(xa.z*wgt + bia);
    af[3] = (short)f2bf(xa.w*wgt + bia);
    af[4] = (short)f2bf(xb.x*wgt + bia);
    af[5] = (short)f2bf(xb.y*wgt + bia);
    af[6] = (short)f2bf(xb.z*wgt + bia);
    af[7] = (short)f2bf(xb.w*wgt + bia);
    #pragma unroll
    for (int nf = 0; nf < 4; ++nf){
      int dp = ch*64 + nf*16 + l15;
      bfrag8 bf = *reinterpret_cast<const bfrag8*>(
          lds + dp*128 + ((((ks*4 + grp)*8)) ^ ((dp&15)<<3)));
      acc[nf] = __builtin_amdgcn_mfma_f32_16x16x32_bf16(af, bf, acc[nf], 0, 0, 0);
    }
  }

  // per-row partial (s, qq) over this wave's 64 cols -> LDS exchange
  #pragma unroll
  for (int r = 0; r < 4; ++r){
    float s = 0.f, qq = 0.f;
    #pragma unroll
    for (int nf = 0; nf < 4; ++nf){ float v = acc[nf][r]; s += v; qq += v*v; }
    #pragma unroll
    for (int m = 1; m < 16; m <<= 1){ s += __shfl_xor(s, m); qq += __shfl_xor(qq, m); }
    if (l15 == 0) lnx[ch*64 + rh*16 + grp*4 + r] = make_float2(s, qq);
  }
  __syncthreads();

  float gc[4], bc[4];
  #pragma unroll
  for (int nf = 0; nf < 4; ++nf){
    int col = ch*64 + nf*16 + l15;
    gc[nf] = gamma[col]; bc[nf] = beta[col];
  }

  // C/D layout: col = lane&15, row = (lane>>4)*4 + r (m89-verified)
  #pragma unroll
  for (int r = 0; r < 4; ++r){
    const int lrow = rh*16 + grp*4 + r;
    float2 pa = lnx[lrow], pb = lnx[64 + lrow];
    float s = pa.x + pb.x, qq = pa.y + pb.y;
    float mu = s * 0.0078125f;
    float var = fmaxf(qq*0.0078125f - mu*mu, 0.f);
    float rstd = rsqrtf(var + 1e-5f);
    const int rC = blockIdx.x*64 + lrow;
    #pragma unroll
    for (int nf = 0; nf < 4; ++nf){
      float hn = (acc[nf][r] - mu)*rstd*gc[nf] + bc[nf];
      acc[nf][r] = hn;
      h_lnB[(size_t)rC*DD + ch*64 + nf*16 + l15] = f2bf(hn);
    }
  }

  __syncthreads();   // WT/x no longer needed; reuse smem as hb[64 n][128 d] bf16
  #pragma unroll
  for (int r = 0; r < 4; ++r)
    #pragma unroll
    for (int nf = 0; nf < 4; ++nf)
      lds[(rh*16 + grp*4 + r)*128 + ch*64 + nf*16 + l15] = f2bf(acc[nf][r]);
  __syncthreads();

  // i8-quantize transpose write: thread (d = tid&127, q4 = tid>>7) -> 16 n's
  {
    const int r0 = blockIdx.x*64;
    const int bB = r0 >> 12;
    const int nt = (r0 & 4095) >> 6;
    char* dstt = hTi8 + (((size_t)(bB*64 + nt)*128) << 6);
    const int d = tid & 127, q4 = tid >> 7;
    int pk[4];
    #pragma unroll
    for (int j = 0; j < 4; ++j){
      U32 word = 0;
      #pragma unroll
      for (int c = 0; c < 4; ++c){
        float v = bf2f((U32)lds[(q4*16 + j*4 + c)*128 + d]);
        float qf = fminf(fmaxf(rintf(v*32.f), -127.f), 127.f);
        int qi = (int)qf;
        word |= ((U32)(qi & 0xFF)) << (c*8);
      }
      pk[j] = (int)word;
    }
    int4 pa; pa.x = pk[0]; pa.y = pk[1]; pa.z = pk[2]; pa.w = pk[3];
    *reinterpret_cast<int4*>(dstt + (size_t)d*64 + q4*16) = pa;
  }
}

// ---------------- kernel 2: S = mask@h via i8 MFMA (K=64), exact i32 combine ----
// FROZEN from R15 (43.3µs): 8 waves = K-eighths, direct-to-reg B, 2-banked
// prefetch, no main-loop barriers, XCD-pinned batch.
__global__ __launch_bounds__(512, 2) void k2_main(
    const U32* __restrict__ adjbT, const char* __restrict__ hTi8,
    const U16* __restrict__ h_lnB, float* __restrict__ out)
{
  __shared__ int part[32768];                // 128 KB: 4 regions x [64 r][128 c] i32
  const int tid = threadIdx.x;
  const int lane = tid & 63, w = tid >> 6;   // w = K-eighth
  const int l15 = lane & 15, grp = lane >> 4;
  const int bid = blockIdx.x;
  const int xcd = bid & 7;
  const int b = xcd >> 1;                    // batch pinned to XCD pair
  const int iblk = (((bid >> 3) << 1) | (xcd & 1)) * 64;
  const float CM2 = 0.2f * -9.0e15f / 32.0f; // leaky(MASK_VAL) / quant scale
  const U32 MUL = 0x00204081u;

  const U32* ar0 = adjbT + (size_t)(w*16)*4096 + iblk +      l15;
  const U32* ar1 = adjbT + (size_t)(w*16)*4096 + iblk + 16 + l15;
  const U32* ar2 = adjbT + (size_t)(w*16)*4096 + iblk + 32 + l15;
  const U32* ar3 = adjbT + (size_t)(w*16)*4096 + iblk + 48 + l15;

  const char* bp = hTi8 + (((size_t)(b*64 + w*8)*128) << 6) + l15*64 + grp*16;

  i32x4 acc[4][8] = {};

#define LOADB(P0,P1,P2,P3,P4,P5,P6,P7, S) do { \
    const char* _q = bp + (size_t)(S)*8192; \
    P0 = *reinterpret_cast<const i32x4*>(_q);        \
    P1 = *reinterpret_cast<const i32x4*>(_q + 1024); \
    P2 = *reinterpret_cast<const i32x4*>(_q + 2048); \
    P3 = *reinterpret_cast<const i32x4*>(_q + 3072); \
    P4 = *reinterpret_cast<const i32x4*>(_q + 4096); \
    P5 = *reinterpret_cast<const i32x4*>(_q + 5120); \
    P6 = *reinterpret_cast<const i32x4*>(_q + 6144); \
    P7 = *reinterpret_cast<const i32x4*>(_q + 7168); } while(0)

#define LOADW(L0,H0,L1,H1,L2,H2,L3,H3, S) do { \
    L0 = ar0[(size_t)(2*(S))*4096];   H0 = ar0[(size_t)(2*(S)+1)*4096]; \
    L1 = ar1[(size_t)(2*(S))*4096];   H1 = ar1[(size_t)(2*(S)+1)*4096]; \
    L2 = ar2[(size_t)(2*(S))*4096];   H2 = ar2[(size_t)(2*(S)+1)*4096]; \
    L3 = ar3[(size_t)(2*(S))*4096];   H3 = ar3[(size_t)(2*(S)+1)*4096]; } while(0)

#define COLM(CF, NF) do { \
    acc[0][NF] = __builtin_amdgcn_mfma_i32_16x16x64_i8(a0, CF, acc[0][NF], 0,0,0); \
    acc[1][NF] = __builtin_amdgcn_mfma_i32_16x16x64_i8(a1, CF, acc[1][NF], 0,0,0); \
    acc[2][NF] = __builtin_amdgcn_mfma_i32_16x16x64_i8(a2, CF, acc[2][NF], 0,0,0); \
    acc[3][NF] = __builtin_amdgcn_mfma_i32_16x16x64_i8(a3, CF, acc[3][NF], 0,0,0); } while(0)

#define COMPUTE(P0,P1,P2,P3,P4,P5,P6,P7, L0,H0,L1,H1,L2,H2,L3,H3) do { \
    i32x4 a0 = afragi8(L0, H0, grp, MUL); \
    i32x4 a1 = afragi8(L1, H1, grp, MUL); \
    i32x4 a2 = afragi8(L2, H2, grp, MUL); \
    i32x4 a3 = afragi8(L3, H3, grp, MUL); \
    COLM(P0, 0); COLM(P1, 1); COLM(P2, 2); COLM(P3, 3); \
    COLM(P4, 4); COLM(P5, 5); COLM(P6, 6); COLM(P7, 7); } while(0)

  i32x4 A0,A1,A2,A3,A4,A5,A6,A7, B0,B1,B2,B3,B4,B5,B6,B7;
  U32 aL0,aH0,aL1,aH1,aL2,aH2,aL3,aH3;
  U32 bL0,bH0,bL1,bH1,bL2,bH2,bL3,bH3;

  LOADB(A0,A1,A2,A3,A4,A5,A6,A7, 0);
  LOADW(aL0,aH0,aL1,aH1,aL2,aH2,aL3,aH3, 0);

  #pragma unroll 1
  for (int it = 0; it < 4; ++it){
    const int s = it*2;
    LOADB(B0,B1,B2,B3,B4,B5,B6,B7, s+1);
    LOADW(bL0,bH0,bL1,bH1,bL2,bH2,bL3,bH3, s+1);
    COMPUTE(A0,A1,A2,A3,A4,A5,A6,A7, aL0,aH0,aL1,aH1,aL2,aH2,aL3,aH3);
    LOADB(A0,A1,A2,A3,A4,A5,A6,A7, s+2);     // s+2==8 on last iter: reads pad
    LOADW(aL0,aH0,aL1,aH1,aL2,aH2,aL3,aH3, s+2);
    COMPUTE(B0,B1,B2,B3,B4,B5,B6,B7, bL0,bH0,bL1,bH1,bL2,bH2,bL3,bH3);
  }

  // ---- exact i32 K-combine: 4 regions; waves 0-3 write, 4-7 RMW-add ----
  {
    int* reg = part + (w & 3)*8192;          // region = [64 r][128 c] i32
    if (w < 4){
      #pragma unroll
      for (int f = 0; f < 4; ++f)
        #pragma unroll
        for (int nf = 0; nf < 8; ++nf){
          const int col = nf*16 + l15;
          #pragma unroll
          for (int r = 0; r < 4; ++r){
            const int lr = f*16 + grp*4 + r;
            reg[lr*128 + (col ^ (((lr>>2)&3)<<4))] = acc[f][nf][r];
          }
        }
    }
    __syncthreads();
    if (w >= 4){
      #pragma unroll
      for (int f = 0; f < 4; ++f)
        #pragma unroll
        for (int nf = 0; nf < 8; ++nf){
          const int col = nf*16 + l15;
          #pragma unroll
          for (int r = 0; r < 4; ++r){
            const int lr = f*16 + grp*4 + r;
            const int idx = lr*128 + (col ^ (((lr>>2)&3)<<4));
            reg[idx] += acc[f][nf][r];
          }
        }
    }
    __syncthreads();
  }

  // ---- epilogue: 8 rows/wave, sum 4 regions, elu + residual ----
  #pragma unroll
  for (int rr = 0; rr < 8; ++rr){
    const int row = w*8 + rr;
    const int sw = ((row>>2)&3)<<4;
    const int idx = row*128 + ((2*lane) ^ sw);  // pair-safe: sw has no bit0
    int s0 = 0, s1 = 0;
    #pragma unroll
    for (int q = 0; q < 4; ++q){
      int2 v = *reinterpret_cast<const int2*>(part + q*8192 + idx);
      s0 += v.x; s1 += v.y;
    }
    const float h0 = CM2 * (float)s0, h1 = CM2 * (float)s1;
    const float e0 = h0 > 0.f ? h0 : __expf(h0) - 1.f;
    const float e1 = h1 > 0.f ? h1 : __expf(h1) - 1.f;
    const size_t o = ((size_t)b*NN + iblk + row)*DD + 2*lane;
    const U32 hl = *reinterpret_cast<const U32*>(h_lnB + o);
    float2 ov; ov.x = e0 + bf2f(hl & 0xffffu); ov.y = e1 + bf2f(hl >> 16);
    *reinterpret_cast<float2*>(out + o) = ov;
  }
#undef COLM
#undef COMPUTE
#undef LOADW
#undef LOADB
}

extern "C" void kernel_launch(void* const* d_in, const int* in_sizes, int n_in,
                              void* d_out, int out_size, void* d_ws, size_t ws_size,
                              hipStream_t stream) {
  const float* x     = (const float*)d_in[0];
  const int*   adj   = (const int*)  d_in[1];
  const float* W     = (const float*)d_in[2];
  const float* nw    = (const float*)d_in[5];
  const float* nb    = (const float*)d_in[6];
  const float* gamma = (const float*)d_in[7];
  const float* beta  = (const float*)d_in[8];
  float* out = (float*)d_out;

  char* ws = (char*)d_ws;
  U16*  h_lnB = (U16*)(ws);                             // 4 MB
  char* hTi8  = (char*)(ws + 4*1024*1024);              // 2 MB + 16 KB pad
  U16*  WT    = (U16*)(ws + 6*1024*1024 + 64*1024);     // 32 KB
  U32*  adjbT = (U32*)(ws + 7*1024*1024);               // 2 MB + 64 KB pad

  k0_combo<<<dim3(2112), dim3(256), 0, stream>>>(adj, adjbT, W, WT);
  k1_prep <<<dim3(256),  dim3(512), 0, stream>>>(x, WT, nw, nb, gamma, beta,
                                                 h_lnB, hTi8);
  k2_main <<<dim3(256),  dim3(512), 0, stream>>>(adjbT, hTi8, h_lnB, out);
}